// Round 1
// baseline (2501.266 us; speedup 1.0000x reference)
//
#include <hip/hip_runtime.h>
#include <hip/hip_bf16.h>
#include <math.h>

#define CDIV(a,b) (((a)+(b)-1)/(b))

// ---------------------------------------------------------------------------
// CSR build (by destination node). Edges = [E graph edges] + [n self-loops].
// ---------------------------------------------------------------------------
__global__ void hist_kernel(const int* __restrict__ ei, int* __restrict__ deg,
                            int E, int Et) {
    int e = blockIdx.x * blockDim.x + threadIdx.x;
    if (e >= Et) return;
    int d = (e < E) ? ei[E + e] : (e - E);
    atomicAdd(&deg[d], 1);
}

// Single-block exclusive scan over deg[0..n) -> off[0..n]
__global__ void scan_kernel(const int* __restrict__ deg, int* __restrict__ off, int n) {
    __shared__ int buf[1024];
    __shared__ int carry_s;
    int t = threadIdx.x;
    if (t == 0) carry_s = 0;
    __syncthreads();
    for (int base = 0; base < n; base += 1024) {
        int v = (base + t < n) ? deg[base + t] : 0;
        buf[t] = v;
        __syncthreads();
        for (int s = 1; s < 1024; s <<= 1) {
            int x = (t >= s) ? buf[t - s] : 0;
            __syncthreads();
            buf[t] += x;
            __syncthreads();
        }
        int incl = buf[t];
        int carry = carry_s;
        __syncthreads();
        if (t == 1023) carry_s = carry + incl;
        if (base + t < n) off[base + t] = carry + incl - v;
        __syncthreads();
    }
    if (t == 0) off[n] = carry_s;
}

__global__ void scatter_kernel(const int* __restrict__ ei, const int* __restrict__ off,
                               int* __restrict__ cur, int* __restrict__ csr,
                               int E, int Et) {
    int e = blockIdx.x * blockDim.x + threadIdx.x;
    if (e >= Et) return;
    int s, d;
    if (e < E) { s = ei[e]; d = ei[E + e]; } else { s = e - E; d = s; }
    int pos = off[d] + atomicAdd(&cur[d], 1);
    csr[pos] = s;
}

// ---------------------------------------------------------------------------
// fp32 GEMM: C[M,N] = A[M,K] @ B[K,N] (+bias). 128x128 tile, BK=16,
// 256 threads, 8x8 per-thread microtile. N % 128 == 0, K % 16 == 0.
// ---------------------------------------------------------------------------
__global__ __launch_bounds__(256) void gemm_kernel(
    const float* __restrict__ A, const float* __restrict__ B,
    const float* __restrict__ bias, float* __restrict__ C,
    int M, int N, int K)
{
    __shared__ float As[16][132];   // transposed A tile: As[k][m], padded row
    __shared__ float Bs[16][128];
    int t  = threadIdx.x;
    int m0 = blockIdx.x * 128, n0 = blockIdx.y * 128;
    int tx = t & 15, ty = t >> 4;
    int ar = t >> 1, ac = (t & 1) * 8;     // A tile: 128 rows x 16 k
    int br = t >> 4, bc = (t & 15) * 8;    // B tile: 16 k x 128 cols

    float acc[8][8];
#pragma unroll
    for (int i = 0; i < 8; i++)
#pragma unroll
        for (int j = 0; j < 8; j++) acc[i][j] = 0.f;

    bool avalid = (m0 + ar) < M;
    const float* Arow = A + (size_t)(m0 + ar) * K;

    for (int k0 = 0; k0 < K; k0 += 16) {
        float4 a0, a1;
        if (avalid) {
            a0 = *(const float4*)(Arow + k0 + ac);
            a1 = *(const float4*)(Arow + k0 + ac + 4);
        } else {
            a0 = make_float4(0.f, 0.f, 0.f, 0.f);
            a1 = a0;
        }
        As[ac + 0][ar] = a0.x; As[ac + 1][ar] = a0.y;
        As[ac + 2][ar] = a0.z; As[ac + 3][ar] = a0.w;
        As[ac + 4][ar] = a1.x; As[ac + 5][ar] = a1.y;
        As[ac + 6][ar] = a1.z; As[ac + 7][ar] = a1.w;
        const float* Brow = B + (size_t)(k0 + br) * N + n0 + bc;
        *(float4*)&Bs[br][bc]     = *(const float4*)(Brow);
        *(float4*)&Bs[br][bc + 4] = *(const float4*)(Brow + 4);
        __syncthreads();
#pragma unroll
        for (int k = 0; k < 16; k++) {
            float4 a0v = *(const float4*)&As[k][ty * 8];
            float4 a1v = *(const float4*)&As[k][ty * 8 + 4];
            float4 b0v = *(const float4*)&Bs[k][tx * 8];
            float4 b1v = *(const float4*)&Bs[k][tx * 8 + 4];
            float av[8] = {a0v.x, a0v.y, a0v.z, a0v.w, a1v.x, a1v.y, a1v.z, a1v.w};
            float bv[8] = {b0v.x, b0v.y, b0v.z, b0v.w, b1v.x, b1v.y, b1v.z, b1v.w};
#pragma unroll
            for (int i = 0; i < 8; i++)
#pragma unroll
                for (int j = 0; j < 8; j++)
                    acc[i][j] = fmaf(av[i], bv[j], acc[i][j]);
        }
        __syncthreads();
    }

#pragma unroll
    for (int i = 0; i < 8; i++) {
        int row = m0 + ty * 8 + i;
        if (row >= M) continue;
        float* Crow = C + (size_t)row * N + n0 + tx * 8;
#pragma unroll
        for (int j = 0; j < 8; j++) {
            float v = acc[i][j];
            if (bias) v += bias[n0 + tx * 8 + j];
            Crow[j] = v;
        }
    }
}

// ---------------------------------------------------------------------------
// es[n,h] = dot(h[n,h,:], a_src[h,:]);  ed likewise.  C = 512, one wave/head.
// block = H*64 threads, grid = n
// ---------------------------------------------------------------------------
__global__ void esed_kernel(const float* __restrict__ h, const float* __restrict__ a_src,
                            const float* __restrict__ a_dst, float* __restrict__ es,
                            float* __restrict__ ed, int H) {
    int nidx = blockIdx.x;
    int t = threadIdx.x;
    int head = t >> 6, lane = t & 63;
    const float* hp = h + (size_t)nidx * H * 512 + head * 512 + lane * 8;
    const float* sp = a_src + head * 512 + lane * 8;
    const float* dp = a_dst + head * 512 + lane * 8;
    float4 h0 = *(const float4*)hp,       h1 = *(const float4*)(hp + 4);
    float4 s0 = *(const float4*)sp,       s1 = *(const float4*)(sp + 4);
    float4 d0 = *(const float4*)dp,       d1 = *(const float4*)(dp + 4);
    float s = h0.x * s0.x + h0.y * s0.y + h0.z * s0.z + h0.w * s0.w
            + h1.x * s1.x + h1.y * s1.y + h1.z * s1.z + h1.w * s1.w;
    float d = h0.x * d0.x + h0.y * d0.y + h0.z * d0.z + h0.w * d0.w
            + h1.x * d1.x + h1.y * d1.y + h1.z * d1.z + h1.w * d1.w;
    for (int o = 32; o; o >>= 1) { s += __shfl_down(s, o); d += __shfl_down(d, o); }
    if (lane == 0) { es[nidx * H + head] = s; ed[nidx * H + head] = d; }
}

// ---------------------------------------------------------------------------
// Aggregation: one block per (dst, head). Softmax (no max-shift, safe range)
// + weighted sum over in-edges + normalize + bias + optional ELU.
// block = 256 threads, each handles c and c+256 of C=512.
// ---------------------------------------------------------------------------
__global__ __launch_bounds__(256) void agg_kernel(
    const float* __restrict__ h, const float* __restrict__ es,
    const float* __restrict__ ed, const int* __restrict__ csr,
    const int* __restrict__ off, const float* __restrict__ bias,
    float* __restrict__ out, int H, int do_elu)
{
    int d = blockIdx.x, head = blockIdx.y, t = threadIdx.x;
    int HS = H * 512;
    float edd = ed[d * H + head];
    int beg = off[d], end = off[d + 1];
    float acc0 = 0.f, acc1 = 0.f, den = 0.f;
    const float* hb = h + head * 512;
    for (int i = beg; i < end; i++) {
        int s = csr[i];
        float e = es[s * H + head] + edd;
        e = (e > 0.f) ? e : 0.2f * e;           // leaky_relu(0.2)
        float w = __expf(e);
        den += w;
        const float* hp = hb + (size_t)s * HS;
        acc0 = fmaf(w, hp[t],       acc0);
        acc1 = fmaf(w, hp[t + 256], acc1);
    }
    float inv = 1.f / den;                       // den >= self-loop term > 0
    float v0 = acc0 * inv, v1 = acc1 * inv;
    if (bias) { v0 += bias[head * 512 + t]; v1 += bias[head * 512 + t + 256]; }
    if (do_elu) {
        v0 = (v0 > 0.f) ? v0 : expm1f(v0);
        v1 = (v1 > 0.f) ? v1 : expm1f(v1);
    }
    out[(size_t)d * HS + head * 512 + t]       = v0;
    out[(size_t)d * HS + head * 512 + t + 256] = v1;
}

// Layer 3: mean over 2 heads + bias -> d_out [n,512]
__global__ void mean_bias_kernel(const float* __restrict__ T, const float* __restrict__ b,
                                 float* __restrict__ out, int total) {
    int i = blockIdx.x * blockDim.x + threadIdx.x;
    if (i >= total) return;
    int c = i & 511;
    int r = i >> 9;
    out[i] = 0.5f * (T[(size_t)r * 1024 + c] + T[(size_t)r * 1024 + 512 + c]) + b[c];
}

// ---------------------------------------------------------------------------
extern "C" void kernel_launch(void* const* d_in, const int* in_sizes, int n_in,
                              void* d_out, int out_size, void* d_ws, size_t ws_size,
                              hipStream_t stream) {
    const float* x      = (const float*)d_in[0];
    const int*   ei     = (const int*)  d_in[1];
    const float* proj_w = (const float*)d_in[2];
    const float* proj_b = (const float*)d_in[3];
    const float* w1  = (const float*)d_in[4];
    const float* as1 = (const float*)d_in[5];
    const float* ad1 = (const float*)d_in[6];
    const float* b1  = (const float*)d_in[7];
    const float* w2  = (const float*)d_in[8];
    const float* as2 = (const float*)d_in[9];
    const float* ad2 = (const float*)d_in[10];
    const float* b2  = (const float*)d_in[11];
    const float* w3  = (const float*)d_in[12];
    const float* as3 = (const float*)d_in[13];
    const float* ad3 = (const float*)d_in[14];
    const float* b3  = (const float*)d_in[15];

    const int n  = in_sizes[0] / 256;   // 10000
    const int E  = in_sizes[1] / 2;     // 160000
    const int Et = E + n;               // 170000

    // workspace carve (256B aligned)
    char* p = (char*)d_ws;
    auto carve = [&](size_t bytes) {
        void* r = (void*)p;
        p += (bytes + 255) & ~(size_t)255;
        return r;
    };
    float* bufA = (float*)carve((size_t)n * 2048 * sizeof(float));  // 80 MB
    float* bufB = (float*)carve((size_t)n * 2048 * sizeof(float));  // 80 MB
    float* es   = (float*)carve((size_t)n * 4 * sizeof(float));
    float* ed   = (float*)carve((size_t)n * 4 * sizeof(float));
    int* deg = (int*)carve((size_t)n * sizeof(int));
    int* cur = (int*)carve((size_t)n * sizeof(int));
    int* off = (int*)carve((size_t)(n + 1) * sizeof(int));
    int* csr = (int*)carve((size_t)Et * sizeof(int));
    (void)ws_size; (void)n_in;

    // --- CSR build ---
    hipMemsetAsync(deg, 0, n * sizeof(int), stream);
    hipMemsetAsync(cur, 0, n * sizeof(int), stream);
    hist_kernel<<<CDIV(Et, 256), 256, 0, stream>>>(ei, deg, E, Et);
    scan_kernel<<<1, 1024, 0, stream>>>(deg, off, n);
    scatter_kernel<<<CDIV(Et, 256), 256, 0, stream>>>(ei, off, cur, csr, E, Et);

    const int MB = CDIV(n, 128);  // 79

    // --- proj: bufA = x @ proj_w + proj_b   [n,512] ---
    gemm_kernel<<<dim3(MB, 512 / 128), 256, 0, stream>>>(x, proj_w, proj_b, bufA, n, 512, 256);

    // --- layer 1 (H=4, concat, ELU) ---
    gemm_kernel<<<dim3(MB, 2048 / 128), 256, 0, stream>>>(bufA, w1, nullptr, bufB, n, 2048, 512);
    esed_kernel<<<n, 4 * 64, 0, stream>>>(bufB, as1, ad1, es, ed, 4);
    agg_kernel<<<dim3(n, 4), 256, 0, stream>>>(bufB, es, ed, csr, off, b1, bufA, 4, 1);

    // --- layer 2 (H=4, concat, ELU) ---
    gemm_kernel<<<dim3(MB, 2048 / 128), 256, 0, stream>>>(bufA, w2, nullptr, bufB, n, 2048, 2048);
    esed_kernel<<<n, 4 * 64, 0, stream>>>(bufB, as2, ad2, es, ed, 4);
    agg_kernel<<<dim3(n, 4), 256, 0, stream>>>(bufB, es, ed, csr, off, b2, bufA, 4, 1);

    // --- layer 3 (H=2, mean, no ELU) ---
    gemm_kernel<<<dim3(MB, 1024 / 128), 256, 0, stream>>>(bufA, w3, nullptr, bufB, n, 1024, 2048);
    esed_kernel<<<n, 2 * 64, 0, stream>>>(bufB, as3, ad3, es, ed, 2);
    agg_kernel<<<dim3(n, 2), 256, 0, stream>>>(bufB, es, ed, csr, off, nullptr, bufA, 2, 0);
    mean_bias_kernel<<<CDIV(n * 512, 256), 256, 0, stream>>>(bufA, b3, (float*)d_out, n * 512);
}

// Round 2
// 952.415 us; speedup vs baseline: 2.6262x; 2.6262x over previous
//
#include <hip/hip_runtime.h>
#include <hip/hip_bf16.h>
#include <math.h>

#define CDIV(a,b) (((a)+(b)-1)/(b))

typedef __bf16  bf16x8 __attribute__((ext_vector_type(8)));
typedef float   f32x4  __attribute__((ext_vector_type(4)));

// ---------------------------------------------------------------------------
// CSR build (by destination node). Edges = [E graph edges] + [n self-loops].
// ---------------------------------------------------------------------------
__global__ void hist_kernel(const int* __restrict__ ei, int* __restrict__ deg,
                            int E, int Et) {
    int e = blockIdx.x * blockDim.x + threadIdx.x;
    if (e >= Et) return;
    int d = (e < E) ? ei[E + e] : (e - E);
    atomicAdd(&deg[d], 1);
}

__global__ void scan_kernel(const int* __restrict__ deg, int* __restrict__ off, int n) {
    __shared__ int buf[1024];
    __shared__ int carry_s;
    int t = threadIdx.x;
    if (t == 0) carry_s = 0;
    __syncthreads();
    for (int base = 0; base < n; base += 1024) {
        int v = (base + t < n) ? deg[base + t] : 0;
        buf[t] = v;
        __syncthreads();
        for (int s = 1; s < 1024; s <<= 1) {
            int x = (t >= s) ? buf[t - s] : 0;
            __syncthreads();
            buf[t] += x;
            __syncthreads();
        }
        int incl = buf[t];
        int carry = carry_s;
        __syncthreads();
        if (t == 1023) carry_s = carry + incl;
        if (base + t < n) off[base + t] = carry + incl - v;
        __syncthreads();
    }
    if (t == 0) off[n] = carry_s;
}

__global__ void scatter_kernel(const int* __restrict__ ei, const int* __restrict__ off,
                               int* __restrict__ cur, int* __restrict__ csr,
                               int E, int Et) {
    int e = blockIdx.x * blockDim.x + threadIdx.x;
    if (e >= Et) return;
    int s, d;
    if (e < E) { s = ei[e]; d = ei[E + e]; } else { s = e - E; d = s; }
    int pos = off[d] + atomicAdd(&cur[d], 1);
    csr[pos] = s;
}

// ---------------------------------------------------------------------------
// Weight transpose + fp32 -> bf16:  wt[N,K] <- w[K,N]
// ---------------------------------------------------------------------------
__global__ void wt_transpose_kernel(const float* __restrict__ w,
                                    __hip_bfloat16* __restrict__ wt,
                                    int K, int N) {
    __shared__ float tile[32][33];
    int kb = blockIdx.x * 32, nb = blockIdx.y * 32;
    int tx = threadIdx.x & 31, ty = threadIdx.x >> 5;   // 256 threads, ty 0..7
    for (int i = ty; i < 32; i += 8)
        tile[i][tx] = w[(size_t)(kb + i) * N + nb + tx];
    __syncthreads();
    for (int i = ty; i < 32; i += 8)
        wt[(size_t)(nb + i) * K + kb + tx] = __float2bfloat16(tile[tx][i]);
}

__global__ void cvt_bf16_kernel(const float* __restrict__ in,
                                __hip_bfloat16* __restrict__ out, int total) {
    int i = blockIdx.x * blockDim.x + threadIdx.x;
    if (i < total) out[i] = __float2bfloat16(in[i]);
}

// ---------------------------------------------------------------------------
// bf16 MFMA GEMM (m97 structure): C[M,N] = A[M,K] @ BT[N,K]^T (+bias)
// 128x128 tile, BK=32, 256 threads (4 waves, each 64x64), 16x16x32 MFMA.
// A: [Mpad,K] bf16 row-major (Mpad = gridDim.x*128, reads may touch pad rows)
// BT: [N,K] bf16 row-major. Output: fp32 Cf or bf16 Cb (rows < M guarded).
// ---------------------------------------------------------------------------
__device__ __forceinline__ void gload16(void* lds, const void* g) {
    __builtin_amdgcn_global_load_lds(
        (const __attribute__((address_space(1))) void*)g,
        (__attribute__((address_space(3))) void*)lds, 16, 0, 0);
}

__global__ __launch_bounds__(256) void gemm_bf16_kernel(
    const __hip_bfloat16* __restrict__ A,
    const __hip_bfloat16* __restrict__ BT,
    const float* __restrict__ bias,
    float* __restrict__ Cf,
    __hip_bfloat16* __restrict__ Cb,
    int M, int N, int K)
{
    __shared__ __align__(16) __hip_bfloat16 As[128 * 32];
    __shared__ __align__(16) __hip_bfloat16 Bs[128 * 32];
    const int tid = threadIdx.x;
    const int m0 = blockIdx.x * 128, n0 = blockIdx.y * 128;
    const int w = tid >> 6, l = tid & 63;
    const int wm = (w & 1) * 64, wn = (w >> 1) * 64;
    const int lm = l & 15, lq = l >> 4;

    f32x4 acc[4][4] = {};

    const int arow = tid >> 2;          // 0..63
    const int acol = (tid & 3) * 8;     // bf16 elems within 32-wide k slab
    const __hip_bfloat16* Ag = A  + (size_t)(m0 + arow) * K + acol;
    const __hip_bfloat16* Bg = BT + (size_t)(n0 + arow) * K + acol;
    char* AsW = (char*)As + (w << 10);  // wave-uniform LDS base
    char* BsW = (char*)Bs + (w << 10);

    for (int k0 = 0; k0 < K; k0 += 32) {
        gload16(AsW,        Ag + k0);
        gload16(AsW + 4096, Ag + (size_t)64 * K + k0);
        gload16(BsW,        Bg + k0);
        gload16(BsW + 4096, Bg + (size_t)64 * K + k0);
        __syncthreads();   // drains vmcnt -> LDS valid
        bf16x8 af[4], bfr[4];
#pragma unroll
        for (int i = 0; i < 4; i++)
            af[i] = *(const bf16x8*)(As + (wm + i * 16 + lm) * 32 + lq * 8);
#pragma unroll
        for (int j = 0; j < 4; j++)
            bfr[j] = *(const bf16x8*)(Bs + (wn + j * 16 + lm) * 32 + lq * 8);
#pragma unroll
        for (int i = 0; i < 4; i++)
#pragma unroll
            for (int j = 0; j < 4; j++)
                acc[i][j] = __builtin_amdgcn_mfma_f32_16x16x32_bf16(
                    af[i], bfr[j], acc[i][j], 0, 0, 0);
        __syncthreads();   // all waves done reading before next overwrite
    }

#pragma unroll
    for (int i = 0; i < 4; i++) {
        int rb = m0 + wm + i * 16 + lq * 4;
#pragma unroll
        for (int r = 0; r < 4; r++) {
            int row = rb + r;
            if (row >= M) continue;
#pragma unroll
            for (int j = 0; j < 4; j++) {
                int col = n0 + wn + j * 16 + lm;
                float v = acc[i][j][r];
                if (bias) v += bias[col];
                if (Cf) Cf[(size_t)row * N + col] = v;
                else    Cb[(size_t)row * N + col] = __float2bfloat16(v);
            }
        }
    }
}

// ---------------------------------------------------------------------------
// es/ed: per-node per-head dot with a_src/a_dst. C=512, one wave per head.
// ---------------------------------------------------------------------------
__global__ void esed_kernel(const float* __restrict__ h, const float* __restrict__ a_src,
                            const float* __restrict__ a_dst, float* __restrict__ es,
                            float* __restrict__ ed, int H) {
    int nidx = blockIdx.x;
    int t = threadIdx.x;
    int head = t >> 6, lane = t & 63;
    const float* hp = h + (size_t)nidx * H * 512 + head * 512 + lane * 8;
    const float* sp = a_src + head * 512 + lane * 8;
    const float* dp = a_dst + head * 512 + lane * 8;
    float4 h0 = *(const float4*)hp,       h1 = *(const float4*)(hp + 4);
    float4 s0 = *(const float4*)sp,       s1 = *(const float4*)(sp + 4);
    float4 d0 = *(const float4*)dp,       d1 = *(const float4*)(dp + 4);
    float s = h0.x * s0.x + h0.y * s0.y + h0.z * s0.z + h0.w * s0.w
            + h1.x * s1.x + h1.y * s1.y + h1.z * s1.z + h1.w * s1.w;
    float d = h0.x * d0.x + h0.y * d0.y + h0.z * d0.z + h0.w * d0.w
            + h1.x * d1.x + h1.y * d1.y + h1.z * d1.z + h1.w * d1.w;
    for (int o = 32; o; o >>= 1) { s += __shfl_down(s, o); d += __shfl_down(d, o); }
    if (lane == 0) { es[nidx * H + head] = s; ed[nidx * H + head] = d; }
}

// ---------------------------------------------------------------------------
// Aggregation: one block per (dst, head). Softmax (no max-shift, safe range)
// + weighted sum + normalize + bias + optional ELU. Output fp32 OR bf16.
// ---------------------------------------------------------------------------
__global__ __launch_bounds__(256) void agg_kernel(
    const float* __restrict__ h, const float* __restrict__ es,
    const float* __restrict__ ed, const int* __restrict__ csr,
    const int* __restrict__ off, const float* __restrict__ bias,
    float* __restrict__ outF, __hip_bfloat16* __restrict__ outB,
    int H, int do_elu)
{
    int d = blockIdx.x, head = blockIdx.y, t = threadIdx.x;
    int HS = H * 512;
    float edd = ed[d * H + head];
    int beg = off[d], end = off[d + 1];
    float acc0 = 0.f, acc1 = 0.f, den = 0.f;
    const float* hb = h + head * 512;
    for (int i = beg; i < end; i++) {
        int s = csr[i];
        float e = es[s * H + head] + edd;
        e = (e > 0.f) ? e : 0.2f * e;            // leaky_relu(0.2)
        float wgt = __expf(e);
        den += wgt;
        const float* hp = hb + (size_t)s * HS;
        acc0 = fmaf(wgt, hp[t],       acc0);
        acc1 = fmaf(wgt, hp[t + 256], acc1);
    }
    float inv = 1.f / den;
    float v0 = acc0 * inv, v1 = acc1 * inv;
    if (bias) { v0 += bias[head * 512 + t]; v1 += bias[head * 512 + t + 256]; }
    if (do_elu) {
        v0 = (v0 > 0.f) ? v0 : expm1f(v0);
        v1 = (v1 > 0.f) ? v1 : expm1f(v1);
    }
    size_t o0 = (size_t)d * HS + head * 512 + t;
    if (outF) { outF[o0] = v0; outF[o0 + 256] = v1; }
    else      { outB[o0] = __float2bfloat16(v0); outB[o0 + 256] = __float2bfloat16(v1); }
}

// Layer 3: mean over 2 heads + bias -> d_out [n,512]
__global__ void mean_bias_kernel(const float* __restrict__ T, const float* __restrict__ b,
                                 float* __restrict__ out, int total) {
    int i = blockIdx.x * blockDim.x + threadIdx.x;
    if (i >= total) return;
    int c = i & 511;
    int r = i >> 9;
    out[i] = 0.5f * (T[(size_t)r * 1024 + c] + T[(size_t)r * 1024 + 512 + c]) + b[c];
}

// ---------------------------------------------------------------------------
extern "C" void kernel_launch(void* const* d_in, const int* in_sizes, int n_in,
                              void* d_out, int out_size, void* d_ws, size_t ws_size,
                              hipStream_t stream) {
    const float* x      = (const float*)d_in[0];
    const int*   ei     = (const int*)  d_in[1];
    const float* proj_w = (const float*)d_in[2];
    const float* proj_b = (const float*)d_in[3];
    const float* w1  = (const float*)d_in[4];
    const float* as1 = (const float*)d_in[5];
    const float* ad1 = (const float*)d_in[6];
    const float* b1  = (const float*)d_in[7];
    const float* w2  = (const float*)d_in[8];
    const float* as2 = (const float*)d_in[9];
    const float* ad2 = (const float*)d_in[10];
    const float* b2  = (const float*)d_in[11];
    const float* w3  = (const float*)d_in[12];
    const float* as3 = (const float*)d_in[13];
    const float* ad3 = (const float*)d_in[14];
    const float* b3  = (const float*)d_in[15];

    const int n    = in_sizes[0] / 256;   // 10000
    const int E    = in_sizes[1] / 2;     // 160000
    const int Et   = E + n;               // 170000
    const int MB   = CDIV(n, 128);        // 79
    const int Mpad = MB * 128;            // 10112

    // workspace carve (256B aligned)
    char* p = (char*)d_ws;
    auto carve = [&](size_t bytes) {
        void* r = (void*)p;
        p += (bytes + 255) & ~(size_t)255;
        return r;
    };
    float*          h      = (float*)carve((size_t)n * 2048 * sizeof(float));            // 80 MB
    __hip_bfloat16* act_bf = (__hip_bfloat16*)carve((size_t)Mpad * 2048 * sizeof(__hip_bfloat16)); // 41.4 MB
    __hip_bfloat16* x_bf   = (__hip_bfloat16*)carve((size_t)Mpad * 256 * sizeof(__hip_bfloat16));
    __hip_bfloat16* h0_bf  = (__hip_bfloat16*)carve((size_t)Mpad * 512 * sizeof(__hip_bfloat16));
    __hip_bfloat16* pwt    = (__hip_bfloat16*)carve((size_t)512 * 256 * sizeof(__hip_bfloat16));
    __hip_bfloat16* w1t    = (__hip_bfloat16*)carve((size_t)2048 * 512 * sizeof(__hip_bfloat16));
    __hip_bfloat16* w2t    = (__hip_bfloat16*)carve((size_t)2048 * 2048 * sizeof(__hip_bfloat16));
    __hip_bfloat16* w3t    = (__hip_bfloat16*)carve((size_t)1024 * 2048 * sizeof(__hip_bfloat16));
    float* es  = (float*)carve((size_t)n * 4 * sizeof(float));
    float* ed  = (float*)carve((size_t)n * 4 * sizeof(float));
    int* deg = (int*)carve((size_t)n * sizeof(int));
    int* cur = (int*)carve((size_t)n * sizeof(int));
    int* off = (int*)carve((size_t)(n + 1) * sizeof(int));
    int* csr = (int*)carve((size_t)Et * sizeof(int));
    // layer-3 agg output (fp32 [n,1024] = 40MB) overlays act_bf (dead by then)
    float* agg3f = (float*)act_bf;
    (void)ws_size; (void)n_in;

    // --- CSR build ---
    hipMemsetAsync(deg, 0, n * sizeof(int), stream);
    hipMemsetAsync(cur, 0, n * sizeof(int), stream);
    hist_kernel<<<CDIV(Et, 256), 256, 0, stream>>>(ei, deg, E, Et);
    scan_kernel<<<1, 1024, 0, stream>>>(deg, off, n);
    scatter_kernel<<<CDIV(Et, 256), 256, 0, stream>>>(ei, off, cur, csr, E, Et);

    // --- weight transpose+convert, x convert ---
    wt_transpose_kernel<<<dim3(256 / 32, 512 / 32),  256, 0, stream>>>(proj_w, pwt, 256, 512);
    wt_transpose_kernel<<<dim3(512 / 32, 2048 / 32), 256, 0, stream>>>(w1, w1t, 512, 2048);
    wt_transpose_kernel<<<dim3(2048 / 32, 2048 / 32),256, 0, stream>>>(w2, w2t, 2048, 2048);
    wt_transpose_kernel<<<dim3(2048 / 32, 1024 / 32),256, 0, stream>>>(w3, w3t, 2048, 1024);
    cvt_bf16_kernel<<<CDIV(n * 256, 256), 256, 0, stream>>>(x, x_bf, n * 256);

    // --- proj: h0_bf = bf16(x @ proj_w + proj_b)   [n,512] ---
    gemm_bf16_kernel<<<dim3(MB, 512 / 128), 256, 0, stream>>>(
        x_bf, pwt, proj_b, nullptr, h0_bf, n, 512, 256);

    // --- layer 1 (H=4, concat, ELU) ---
    gemm_bf16_kernel<<<dim3(MB, 2048 / 128), 256, 0, stream>>>(
        h0_bf, w1t, nullptr, h, nullptr, n, 2048, 512);
    esed_kernel<<<n, 4 * 64, 0, stream>>>(h, as1, ad1, es, ed, 4);
    agg_kernel<<<dim3(n, 4), 256, 0, stream>>>(h, es, ed, csr, off, b1,
                                               nullptr, act_bf, 4, 1);

    // --- layer 2 (H=4, concat, ELU) ---
    gemm_bf16_kernel<<<dim3(MB, 2048 / 128), 256, 0, stream>>>(
        act_bf, w2t, nullptr, h, nullptr, n, 2048, 2048);
    esed_kernel<<<n, 4 * 64, 0, stream>>>(h, as2, ad2, es, ed, 4);
    agg_kernel<<<dim3(n, 4), 256, 0, stream>>>(h, es, ed, csr, off, b2,
                                               nullptr, act_bf, 4, 1);

    // --- layer 3 (H=2, mean, no ELU) ---
    gemm_bf16_kernel<<<dim3(MB, 1024 / 128), 256, 0, stream>>>(
        act_bf, w3t, nullptr, h, nullptr, n, 1024, 2048);
    esed_kernel<<<n, 2 * 64, 0, stream>>>(h, as3, ad3, es, ed, 2);
    agg_kernel<<<dim3(n, 2), 256, 0, stream>>>(h, es, ed, csr, off, nullptr,
                                               agg3f, nullptr, 2, 0);
    mean_bias_kernel<<<CDIV(n * 512, 256), 256, 0, stream>>>(agg3f, b3, (float*)d_out, n * 512);
}

// Round 3
// 726.781 us; speedup vs baseline: 3.4416x; 1.3105x over previous
//
#include <hip/hip_runtime.h>
#include <hip/hip_bf16.h>
#include <math.h>

#define CDIV(a,b) (((a)+(b)-1)/(b))

typedef __bf16  bf16x8 __attribute__((ext_vector_type(8)));
typedef float   f32x4  __attribute__((ext_vector_type(4)));
typedef unsigned short u16x8 __attribute__((ext_vector_type(8)));
typedef unsigned short u16x4 __attribute__((ext_vector_type(4)));

__device__ __forceinline__ float bf2f(unsigned short u) {
    union { unsigned int i; float f; } x; x.i = ((unsigned int)u) << 16; return x.f;
}
__device__ __forceinline__ unsigned short f2bf(float f) {
    union { float f; unsigned int i; } x; x.f = f;
    unsigned int r = x.i + 0x7fff + ((x.i >> 16) & 1);   // RNE, finite inputs
    return (unsigned short)(r >> 16);
}

// ---------------------------------------------------------------------------
// CSR build (by destination node). Edges = [E graph edges] + [n self-loops].
// ---------------------------------------------------------------------------
__global__ void hist_kernel(const int* __restrict__ ei, int* __restrict__ deg,
                            int E, int Et) {
    int e = blockIdx.x * blockDim.x + threadIdx.x;
    if (e >= Et) return;
    int d = (e < E) ? ei[E + e] : (e - E);
    atomicAdd(&deg[d], 1);
}

__global__ void scan_kernel(const int* __restrict__ deg, int* __restrict__ off, int n) {
    __shared__ int buf[1024];
    __shared__ int carry_s;
    int t = threadIdx.x;
    if (t == 0) carry_s = 0;
    __syncthreads();
    for (int base = 0; base < n; base += 1024) {
        int v = (base + t < n) ? deg[base + t] : 0;
        buf[t] = v;
        __syncthreads();
        for (int s = 1; s < 1024; s <<= 1) {
            int x = (t >= s) ? buf[t - s] : 0;
            __syncthreads();
            buf[t] += x;
            __syncthreads();
        }
        int incl = buf[t];
        int carry = carry_s;
        __syncthreads();
        if (t == 1023) carry_s = carry + incl;
        if (base + t < n) off[base + t] = carry + incl - v;
        __syncthreads();
    }
    if (t == 0) off[n] = carry_s;
}

__global__ void scatter_kernel(const int* __restrict__ ei, const int* __restrict__ off,
                               int* __restrict__ cur, int* __restrict__ csr,
                               int E, int Et) {
    int e = blockIdx.x * blockDim.x + threadIdx.x;
    if (e >= Et) return;
    int s, d;
    if (e < E) { s = ei[e]; d = ei[E + e]; } else { s = e - E; d = s; }
    int pos = off[d] + atomicAdd(&cur[d], 1);
    csr[pos] = s;
}

// ---------------------------------------------------------------------------
// Weight transpose + fp32 -> bf16:  wt[N,K] <- w[K,N]
// ---------------------------------------------------------------------------
__global__ void wt_transpose_kernel(const float* __restrict__ w,
                                    __hip_bfloat16* __restrict__ wt,
                                    int K, int N) {
    __shared__ float tile[32][33];
    int kb = blockIdx.x * 32, nb = blockIdx.y * 32;
    int tx = threadIdx.x & 31, ty = threadIdx.x >> 5;   // 256 threads
    for (int i = ty; i < 32; i += 8)
        tile[i][tx] = w[(size_t)(kb + i) * N + nb + tx];
    __syncthreads();
    for (int i = ty; i < 32; i += 8)
        wt[(size_t)(nb + i) * K + kb + tx] = __float2bfloat16(tile[tx][i]);
}

__global__ void cvt_bf16_kernel(const float* __restrict__ in,
                                __hip_bfloat16* __restrict__ out, int total) {
    int i = blockIdx.x * blockDim.x + threadIdx.x;
    if (i < total) out[i] = __float2bfloat16(in[i]);
}

// ---------------------------------------------------------------------------
// bf16 MFMA GEMM: Cb[M,N] = bf16(A[M,K] @ BT[N,K]^T (+bias))
// 128x128 tile, BK=32, 256 threads (4 waves, each 64x64), 16x16x32 MFMA.
// ---------------------------------------------------------------------------
__device__ __forceinline__ void gload16(void* lds, const void* g) {
    __builtin_amdgcn_global_load_lds(
        (const __attribute__((address_space(1))) void*)g,
        (__attribute__((address_space(3))) void*)lds, 16, 0, 0);
}

__global__ __launch_bounds__(256) void gemm_bf16_kernel(
    const __hip_bfloat16* __restrict__ A,
    const __hip_bfloat16* __restrict__ BT,
    const float* __restrict__ bias,
    __hip_bfloat16* __restrict__ Cb,
    int M, int N, int K)
{
    __shared__ __align__(16) __hip_bfloat16 As[128 * 32];
    __shared__ __align__(16) __hip_bfloat16 Bs[128 * 32];
    const int tid = threadIdx.x;
    const int m0 = blockIdx.x * 128, n0 = blockIdx.y * 128;
    const int w = tid >> 6, l = tid & 63;
    const int wm = (w & 1) * 64, wn = (w >> 1) * 64;
    const int lm = l & 15, lq = l >> 4;

    f32x4 acc[4][4] = {};

    const int arow = tid >> 2;          // 0..63
    const int acol = (tid & 3) * 8;     // bf16 elems within 32-wide k slab
    const __hip_bfloat16* Ag = A  + (size_t)(m0 + arow) * K + acol;
    const __hip_bfloat16* Bg = BT + (size_t)(n0 + arow) * K + acol;
    char* AsW = (char*)As + (w << 10);  // wave-uniform LDS base
    char* BsW = (char*)Bs + (w << 10);

    for (int k0 = 0; k0 < K; k0 += 32) {
        gload16(AsW,        Ag + k0);
        gload16(AsW + 4096, Ag + (size_t)64 * K + k0);
        gload16(BsW,        Bg + k0);
        gload16(BsW + 4096, Bg + (size_t)64 * K + k0);
        __syncthreads();
        bf16x8 af[4], bfr[4];
#pragma unroll
        for (int i = 0; i < 4; i++)
            af[i] = *(const bf16x8*)(As + (wm + i * 16 + lm) * 32 + lq * 8);
#pragma unroll
        for (int j = 0; j < 4; j++)
            bfr[j] = *(const bf16x8*)(Bs + (wn + j * 16 + lm) * 32 + lq * 8);
#pragma unroll
        for (int i = 0; i < 4; i++)
#pragma unroll
            for (int j = 0; j < 4; j++)
                acc[i][j] = __builtin_amdgcn_mfma_f32_16x16x32_bf16(
                    af[i], bfr[j], acc[i][j], 0, 0, 0);
        __syncthreads();
    }

#pragma unroll
    for (int i = 0; i < 4; i++) {
        int rb = m0 + wm + i * 16 + lq * 4;
#pragma unroll
        for (int r = 0; r < 4; r++) {
            int row = rb + r;
            if (row >= M) continue;
#pragma unroll
            for (int j = 0; j < 4; j++) {
                int col = n0 + wn + j * 16 + lm;
                float v = acc[i][j][r];
                if (bias) v += bias[col];
                Cb[(size_t)row * N + col] = __float2bfloat16(v);
            }
        }
    }
}

// ---------------------------------------------------------------------------
// es/ed: per-node per-head dot with a_src/a_dst (h in bf16). One wave/head.
// ---------------------------------------------------------------------------
__global__ void esed_kernel(const __hip_bfloat16* __restrict__ h,
                            const float* __restrict__ a_src,
                            const float* __restrict__ a_dst,
                            float* __restrict__ es, float* __restrict__ ed, int H) {
    int nidx = blockIdx.x;
    int t = threadIdx.x;
    int head = t >> 6, lane = t & 63;
    const unsigned short* hp =
        (const unsigned short*)h + (size_t)nidx * H * 512 + head * 512 + lane * 8;
    const float* sp = a_src + head * 512 + lane * 8;
    const float* dp = a_dst + head * 512 + lane * 8;
    u16x8 hv = *(const u16x8*)hp;
    float4 s0 = *(const float4*)sp, s1 = *(const float4*)(sp + 4);
    float4 d0 = *(const float4*)dp, d1 = *(const float4*)(dp + 4);
    float hf[8];
#pragma unroll
    for (int k = 0; k < 8; k++) hf[k] = bf2f(hv[k]);
    float s = hf[0]*s0.x + hf[1]*s0.y + hf[2]*s0.z + hf[3]*s0.w
            + hf[4]*s1.x + hf[5]*s1.y + hf[6]*s1.z + hf[7]*s1.w;
    float d = hf[0]*d0.x + hf[1]*d0.y + hf[2]*d0.z + hf[3]*d0.w
            + hf[4]*d1.x + hf[5]*d1.y + hf[6]*d1.z + hf[7]*d1.w;
    for (int o = 32; o; o >>= 1) { s += __shfl_down(s, o); d += __shfl_down(d, o); }
    if (lane == 0) { es[nidx * H + head] = s; ed[nidx * H + head] = d; }
}

// ---------------------------------------------------------------------------
// Aggregation: ONE block per dst, all heads. Thread t owns channels
// [t*VEC, t*VEC+VEC) of the H*512-wide row (VEC = H*512/256). Each edge:
// one contiguous 16B/8B bf16 load per thread (full 4KB row per edge).
// MEAN variant (layer 3) fuses head-mean + bias -> fp32 out.
// ---------------------------------------------------------------------------
template<int H, int VEC, bool MEAN>
__global__ __launch_bounds__(256) void agg_kernel(
    const __hip_bfloat16* __restrict__ h, const float* __restrict__ es,
    const float* __restrict__ ed, const int* __restrict__ csr,
    const int* __restrict__ off, const float* __restrict__ bias,
    float* __restrict__ outF, __hip_bfloat16* __restrict__ outB, int do_elu)
{
    constexpr int HS = H * 512;
    __shared__ float red[MEAN ? 1024 : 1];
    int d = blockIdx.x, t = threadIdx.x;
    int c0 = t * VEC;
    int head = c0 >> 9;
    float edd = ed[d * H + head];
    int beg = off[d], end = off[d + 1];
    float acc[VEC];
#pragma unroll
    for (int k = 0; k < VEC; k++) acc[k] = 0.f;
    float den = 0.f;
    const unsigned short* hb = (const unsigned short*)h;
    for (int i = beg; i < end; i++) {
        int s = csr[i];
        float e = es[s * H + head] + edd;
        e = (e > 0.f) ? e : 0.2f * e;            // leaky_relu(0.2)
        float w = __expf(e);
        den += w;
        const unsigned short* hp = hb + (size_t)s * HS + c0;
        if constexpr (VEC == 8) {
            u16x8 v = *(const u16x8*)hp;
#pragma unroll
            for (int k = 0; k < 8; k++) acc[k] = fmaf(w, bf2f(v[k]), acc[k]);
        } else {
            u16x4 v = *(const u16x4*)hp;
#pragma unroll
            for (int k = 0; k < VEC; k++) acc[k] = fmaf(w, bf2f(v[k]), acc[k]);
        }
    }
    float inv = 1.f / den;
    if constexpr (!MEAN) {
        u16x8 ov;
#pragma unroll
        for (int k = 0; k < VEC; k++) {
            float v = acc[k] * inv + bias[c0 + k];
            if (do_elu) v = (v > 0.f) ? v : expm1f(v);
            ov[k] = f2bf(v);
        }
        *(u16x8*)((unsigned short*)outB + (size_t)d * HS + c0) = ov;
    } else {
#pragma unroll
        for (int k = 0; k < VEC; k++) red[c0 + k] = acc[k] * inv;
        __syncthreads();
        if (t < 128) {
#pragma unroll
            for (int k = 0; k < 4; k++) {
                int c = t * 4 + k;
                outF[(size_t)d * 512 + c] = 0.5f * (red[c] + red[c + 512]) + bias[c];
            }
        }
    }
}

// ---------------------------------------------------------------------------
extern "C" void kernel_launch(void* const* d_in, const int* in_sizes, int n_in,
                              void* d_out, int out_size, void* d_ws, size_t ws_size,
                              hipStream_t stream) {
    const float* x      = (const float*)d_in[0];
    const int*   ei     = (const int*)  d_in[1];
    const float* proj_w = (const float*)d_in[2];
    const float* proj_b = (const float*)d_in[3];
    const float* w1  = (const float*)d_in[4];
    const float* as1 = (const float*)d_in[5];
    const float* ad1 = (const float*)d_in[6];
    const float* b1  = (const float*)d_in[7];
    const float* w2  = (const float*)d_in[8];
    const float* as2 = (const float*)d_in[9];
    const float* ad2 = (const float*)d_in[10];
    const float* b2  = (const float*)d_in[11];
    const float* w3  = (const float*)d_in[12];
    const float* as3 = (const float*)d_in[13];
    const float* ad3 = (const float*)d_in[14];
    const float* b3  = (const float*)d_in[15];

    const int n    = in_sizes[0] / 256;   // 10000
    const int E    = in_sizes[1] / 2;     // 160000
    const int Et   = E + n;               // 170000
    const int MB   = CDIV(n, 128);        // 79
    const int Mpad = MB * 128;            // 10112

    char* p = (char*)d_ws;
    auto carve = [&](size_t bytes) {
        void* r = (void*)p;
        p += (bytes + 255) & ~(size_t)255;
        return r;
    };
    __hip_bfloat16* h_bf   = (__hip_bfloat16*)carve((size_t)Mpad * 2048 * sizeof(__hip_bfloat16)); // GEMM out / gather src
    __hip_bfloat16* act_bf = (__hip_bfloat16*)carve((size_t)Mpad * 2048 * sizeof(__hip_bfloat16)); // agg out / GEMM in
    __hip_bfloat16* x_bf   = (__hip_bfloat16*)carve((size_t)Mpad * 256 * sizeof(__hip_bfloat16));
    __hip_bfloat16* h0_bf  = (__hip_bfloat16*)carve((size_t)Mpad * 512 * sizeof(__hip_bfloat16));
    __hip_bfloat16* pwt    = (__hip_bfloat16*)carve((size_t)512 * 256 * sizeof(__hip_bfloat16));
    __hip_bfloat16* w1t    = (__hip_bfloat16*)carve((size_t)2048 * 512 * sizeof(__hip_bfloat16));
    __hip_bfloat16* w2t    = (__hip_bfloat16*)carve((size_t)2048 * 2048 * sizeof(__hip_bfloat16));
    __hip_bfloat16* w3t    = (__hip_bfloat16*)carve((size_t)1024 * 2048 * sizeof(__hip_bfloat16));
    float* es  = (float*)carve((size_t)n * 4 * sizeof(float));
    float* ed  = (float*)carve((size_t)n * 4 * sizeof(float));
    int* deg = (int*)carve((size_t)n * sizeof(int));
    int* cur = (int*)carve((size_t)n * sizeof(int));
    int* off = (int*)carve((size_t)(n + 1) * sizeof(int));
    int* csr = (int*)carve((size_t)Et * sizeof(int));
    (void)ws_size; (void)n_in;

    // --- CSR build ---
    hipMemsetAsync(deg, 0, n * sizeof(int), stream);
    hipMemsetAsync(cur, 0, n * sizeof(int), stream);
    hist_kernel<<<CDIV(Et, 256), 256, 0, stream>>>(ei, deg, E, Et);
    scan_kernel<<<1, 1024, 0, stream>>>(deg, off, n);
    scatter_kernel<<<CDIV(Et, 256), 256, 0, stream>>>(ei, off, cur, csr, E, Et);

    // --- weight transpose+convert, x convert ---
    wt_transpose_kernel<<<dim3(256 / 32, 512 / 32),  256, 0, stream>>>(proj_w, pwt, 256, 512);
    wt_transpose_kernel<<<dim3(512 / 32, 2048 / 32), 256, 0, stream>>>(w1, w1t, 512, 2048);
    wt_transpose_kernel<<<dim3(2048 / 32, 2048 / 32),256, 0, stream>>>(w2, w2t, 2048, 2048);
    wt_transpose_kernel<<<dim3(2048 / 32, 1024 / 32),256, 0, stream>>>(w3, w3t, 2048, 1024);
    cvt_bf16_kernel<<<CDIV(n * 256, 256), 256, 0, stream>>>(x, x_bf, n * 256);

    // --- proj: h0_bf = bf16(x @ proj_w + proj_b)   [n,512] ---
    gemm_bf16_kernel<<<dim3(MB, 512 / 128), 256, 0, stream>>>(
        x_bf, pwt, proj_b, h0_bf, n, 512, 256);

    // --- layer 1 (H=4, concat, ELU) ---
    gemm_bf16_kernel<<<dim3(MB, 2048 / 128), 256, 0, stream>>>(
        h0_bf, w1t, nullptr, h_bf, n, 2048, 512);
    esed_kernel<<<n, 4 * 64, 0, stream>>>(h_bf, as1, ad1, es, ed, 4);
    agg_kernel<4, 8, false><<<n, 256, 0, stream>>>(h_bf, es, ed, csr, off, b1,
                                                   nullptr, act_bf, 1);

    // --- layer 2 (H=4, concat, ELU) ---
    gemm_bf16_kernel<<<dim3(MB, 2048 / 128), 256, 0, stream>>>(
        act_bf, w2t, nullptr, h_bf, n, 2048, 2048);
    esed_kernel<<<n, 4 * 64, 0, stream>>>(h_bf, as2, ad2, es, ed, 4);
    agg_kernel<4, 8, false><<<n, 256, 0, stream>>>(h_bf, es, ed, csr, off, b2,
                                                   nullptr, act_bf, 1);

    // --- layer 3 (H=2, mean+bias fused, no ELU) ---
    gemm_bf16_kernel<<<dim3(MB, 1024 / 128), 256, 0, stream>>>(
        act_bf, w3t, nullptr, h_bf, n, 1024, 2048);
    esed_kernel<<<n, 2 * 64, 0, stream>>>(h_bf, as3, ad3, es, ed, 2);
    agg_kernel<2, 4, true><<<n, 256, 0, stream>>>(h_bf, es, ed, csr, off, b3,
                                                  (float*)d_out, nullptr, 0);
}

// Round 4
// 676.694 us; speedup vs baseline: 3.6963x; 1.0740x over previous
//
#include <hip/hip_runtime.h>
#include <hip/hip_bf16.h>
#include <math.h>

#define CDIV(a,b) (((a)+(b)-1)/(b))

typedef __bf16  bf16x8 __attribute__((ext_vector_type(8)));
typedef float   f32x4  __attribute__((ext_vector_type(4)));
typedef unsigned short u16x8 __attribute__((ext_vector_type(8)));
typedef unsigned short u16x4 __attribute__((ext_vector_type(4)));

__device__ __forceinline__ float bf2f(unsigned short u) {
    union { unsigned int i; float f; } x; x.i = ((unsigned int)u) << 16; return x.f;
}
__device__ __forceinline__ unsigned short f2bf(float f) {
    union { float f; unsigned int i; } x; x.f = f;
    unsigned int r = x.i + 0x7fff + ((x.i >> 16) & 1);   // RNE, finite inputs
    return (unsigned short)(r >> 16);
}

// ---------------------------------------------------------------------------
// CSR build (by destination node). Edges = [E graph edges] + [n self-loops].
// ---------------------------------------------------------------------------
__global__ void hist_kernel(const int* __restrict__ ei, int* __restrict__ deg,
                            int E, int Et) {
    int e = blockIdx.x * blockDim.x + threadIdx.x;
    if (e >= Et) return;
    int d = (e < E) ? ei[E + e] : (e - E);
    atomicAdd(&deg[d], 1);
}

__global__ void scan_kernel(const int* __restrict__ deg, int* __restrict__ off, int n) {
    __shared__ int buf[1024];
    __shared__ int carry_s;
    int t = threadIdx.x;
    if (t == 0) carry_s = 0;
    __syncthreads();
    for (int base = 0; base < n; base += 1024) {
        int v = (base + t < n) ? deg[base + t] : 0;
        buf[t] = v;
        __syncthreads();
        for (int s = 1; s < 1024; s <<= 1) {
            int x = (t >= s) ? buf[t - s] : 0;
            __syncthreads();
            buf[t] += x;
            __syncthreads();
        }
        int incl = buf[t];
        int carry = carry_s;
        __syncthreads();
        if (t == 1023) carry_s = carry + incl;
        if (base + t < n) off[base + t] = carry + incl - v;
        __syncthreads();
    }
    if (t == 0) off[n] = carry_s;
}

__global__ void scatter_kernel(const int* __restrict__ ei, const int* __restrict__ off,
                               int* __restrict__ cur, int* __restrict__ csr,
                               int E, int Et) {
    int e = blockIdx.x * blockDim.x + threadIdx.x;
    if (e >= Et) return;
    int s, d;
    if (e < E) { s = ei[e]; d = ei[E + e]; } else { s = e - E; d = s; }
    int pos = off[d] + atomicAdd(&cur[d], 1);
    csr[pos] = s;
}

// ---------------------------------------------------------------------------
// Weight transpose + fp32 -> bf16:  wt[N,K] <- w[K,N]
// ---------------------------------------------------------------------------
__global__ void wt_transpose_kernel(const float* __restrict__ w,
                                    __hip_bfloat16* __restrict__ wt,
                                    int K, int N) {
    __shared__ float tile[32][33];
    int kb = blockIdx.x * 32, nb = blockIdx.y * 32;
    int tx = threadIdx.x & 31, ty = threadIdx.x >> 5;   // 256 threads
    for (int i = ty; i < 32; i += 8)
        tile[i][tx] = w[(size_t)(kb + i) * N + nb + tx];
    __syncthreads();
    for (int i = ty; i < 32; i += 8)
        wt[(size_t)(nb + i) * K + kb + tx] = __float2bfloat16(tile[tx][i]);
}

__global__ void cvt_bf16_kernel(const float* __restrict__ in,
                                __hip_bfloat16* __restrict__ out, int total) {
    int i = blockIdx.x * blockDim.x + threadIdx.x;
    if (i < total) out[i] = __float2bfloat16(in[i]);
}

// ---------------------------------------------------------------------------
// bf16 MFMA GEMM: Cb[M,N] = bf16(A[M,K] @ BT[N,K]^T (+bias))
// 128x128 tile, BK=32, 256 threads (4 waves), 16x16x32 MFMA.
// 1-D grid with XCD-aware swizzle: xcd = bid&7 owns a contiguous x-stripe of
// XT M-tiles; within the XCD, slots run x-outer / y-inner so the NB blocks
// sharing an A-tile are consecutive on ONE XCD (A-tile L2-resident, fetched
// once). B (<=8.4 MB) is L3-resident after first touch.
// ---------------------------------------------------------------------------
__device__ __forceinline__ void gload16(void* lds, const void* g) {
    __builtin_amdgcn_global_load_lds(
        (const __attribute__((address_space(1))) void*)g,
        (__attribute__((address_space(3))) void*)lds, 16, 0, 0);
}

__global__ __launch_bounds__(256) void gemm_bf16_kernel(
    const __hip_bfloat16* __restrict__ A,
    const __hip_bfloat16* __restrict__ BT,
    const float* __restrict__ bias,
    __hip_bfloat16* __restrict__ Cb,
    int M, int N, int K, int MB, int NB, int XT)
{
    __shared__ __align__(16) __hip_bfloat16 As[128 * 32];
    __shared__ __align__(16) __hip_bfloat16 Bs[128 * 32];

    const int bid  = blockIdx.x;
    const int xcd  = bid & 7;
    const int slot = bid >> 3;
    const int x_sub = slot / NB;
    const int yb    = slot - x_sub * NB;
    const int xb    = xcd * XT + x_sub;
    if (xb >= MB) return;

    const int tid = threadIdx.x;
    const int m0 = xb * 128, n0 = yb * 128;
    const int w = tid >> 6, l = tid & 63;
    const int wm = (w & 1) * 64, wn = (w >> 1) * 64;
    const int lm = l & 15, lq = l >> 4;

    f32x4 acc[4][4] = {};

    const int arow = tid >> 2;          // 0..63
    const int acol = (tid & 3) * 8;     // bf16 elems within 32-wide k slab
    const __hip_bfloat16* Ag = A  + (size_t)(m0 + arow) * K + acol;
    const __hip_bfloat16* Bg = BT + (size_t)(n0 + arow) * K + acol;
    char* AsW = (char*)As + (w << 10);  // wave-uniform LDS base
    char* BsW = (char*)Bs + (w << 10);

    for (int k0 = 0; k0 < K; k0 += 32) {
        gload16(AsW,        Ag + k0);
        gload16(AsW + 4096, Ag + (size_t)64 * K + k0);
        gload16(BsW,        Bg + k0);
        gload16(BsW + 4096, Bg + (size_t)64 * K + k0);
        __syncthreads();
        bf16x8 af[4], bfr[4];
#pragma unroll
        for (int i = 0; i < 4; i++)
            af[i] = *(const bf16x8*)(As + (wm + i * 16 + lm) * 32 + lq * 8);
#pragma unroll
        for (int j = 0; j < 4; j++)
            bfr[j] = *(const bf16x8*)(Bs + (wn + j * 16 + lm) * 32 + lq * 8);
#pragma unroll
        for (int i = 0; i < 4; i++)
#pragma unroll
            for (int j = 0; j < 4; j++)
                acc[i][j] = __builtin_amdgcn_mfma_f32_16x16x32_bf16(
                    af[i], bfr[j], acc[i][j], 0, 0, 0);
        __syncthreads();
    }

#pragma unroll
    for (int i = 0; i < 4; i++) {
        int rb = m0 + wm + i * 16 + lq * 4;
#pragma unroll
        for (int r = 0; r < 4; r++) {
            int row = rb + r;
            if (row >= M) continue;
#pragma unroll
            for (int j = 0; j < 4; j++) {
                int col = n0 + wn + j * 16 + lm;
                float v = acc[i][j][r];
                if (bias) v += bias[col];
                Cb[(size_t)row * N + col] = __float2bfloat16(v);
            }
        }
    }
}

// ---------------------------------------------------------------------------
// es/ed: per-node per-head dot with a_src/a_dst (h in bf16). One wave/head.
// ---------------------------------------------------------------------------
__global__ void esed_kernel(const __hip_bfloat16* __restrict__ h,
                            const float* __restrict__ a_src,
                            const float* __restrict__ a_dst,
                            float* __restrict__ es, float* __restrict__ ed, int H) {
    int nidx = blockIdx.x;
    int t = threadIdx.x;
    int head = t >> 6, lane = t & 63;
    const unsigned short* hp =
        (const unsigned short*)h + (size_t)nidx * H * 512 + head * 512 + lane * 8;
    const float* sp = a_src + head * 512 + lane * 8;
    const float* dp = a_dst + head * 512 + lane * 8;
    u16x8 hv = *(const u16x8*)hp;
    float4 s0 = *(const float4*)sp, s1 = *(const float4*)(sp + 4);
    float4 d0 = *(const float4*)dp, d1 = *(const float4*)(dp + 4);
    float hf[8];
#pragma unroll
    for (int k = 0; k < 8; k++) hf[k] = bf2f(hv[k]);
    float s = hf[0]*s0.x + hf[1]*s0.y + hf[2]*s0.z + hf[3]*s0.w
            + hf[4]*s1.x + hf[5]*s1.y + hf[6]*s1.z + hf[7]*s1.w;
    float d = hf[0]*d0.x + hf[1]*d0.y + hf[2]*d0.z + hf[3]*d0.w
            + hf[4]*d1.x + hf[5]*d1.y + hf[6]*d1.z + hf[7]*d1.w;
    for (int o = 32; o; o >>= 1) { s += __shfl_down(s, o); d += __shfl_down(d, o); }
    if (lane == 0) { es[nidx * H + head] = s; ed[nidx * H + head] = d; }
}

// ---------------------------------------------------------------------------
// Aggregation: ONE block per dst, all heads. Thread t owns channels
// [t*VEC, t*VEC+VEC). 2x edge unroll for memory-level parallelism.
// MEAN variant (layer 3) fuses head-mean + bias -> fp32 out.
// ---------------------------------------------------------------------------
template<int H, int VEC, bool MEAN>
__global__ __launch_bounds__(256) void agg_kernel(
    const __hip_bfloat16* __restrict__ h, const float* __restrict__ es,
    const float* __restrict__ ed, const int* __restrict__ csr,
    const int* __restrict__ off, const float* __restrict__ bias,
    float* __restrict__ outF, __hip_bfloat16* __restrict__ outB, int do_elu)
{
    constexpr int HS = H * 512;
    __shared__ float red[MEAN ? 1024 : 1];
    int d = blockIdx.x, t = threadIdx.x;
    int c0 = t * VEC;
    int head = c0 >> 9;                       // wave-uniform
    float edd = ed[d * H + head];
    int beg = off[d], end = off[d + 1];
    float acc[VEC];
#pragma unroll
    for (int k = 0; k < VEC; k++) acc[k] = 0.f;
    float den = 0.f;
    const unsigned short* hb = (const unsigned short*)h;

    int i = beg;
    for (; i + 1 < end; i += 2) {
        int s0 = csr[i], s1 = csr[i + 1];
        float e0 = es[s0 * H + head] + edd;
        float e1 = es[s1 * H + head] + edd;
        e0 = (e0 > 0.f) ? e0 : 0.2f * e0;
        e1 = (e1 > 0.f) ? e1 : 0.2f * e1;
        float w0 = __expf(e0), w1 = __expf(e1);
        den += w0 + w1;
        const unsigned short* hp0 = hb + (size_t)s0 * HS + c0;
        const unsigned short* hp1 = hb + (size_t)s1 * HS + c0;
        if constexpr (VEC == 8) {
            u16x8 v0 = *(const u16x8*)hp0;
            u16x8 v1 = *(const u16x8*)hp1;
#pragma unroll
            for (int k = 0; k < 8; k++) acc[k] = fmaf(w0, bf2f(v0[k]), acc[k]);
#pragma unroll
            for (int k = 0; k < 8; k++) acc[k] = fmaf(w1, bf2f(v1[k]), acc[k]);
        } else {
            u16x4 v0 = *(const u16x4*)hp0;
            u16x4 v1 = *(const u16x4*)hp1;
#pragma unroll
            for (int k = 0; k < VEC; k++) acc[k] = fmaf(w0, bf2f(v0[k]), acc[k]);
#pragma unroll
            for (int k = 0; k < VEC; k++) acc[k] = fmaf(w1, bf2f(v1[k]), acc[k]);
        }
    }
    if (i < end) {
        int s0 = csr[i];
        float e0 = es[s0 * H + head] + edd;
        e0 = (e0 > 0.f) ? e0 : 0.2f * e0;
        float w0 = __expf(e0);
        den += w0;
        const unsigned short* hp0 = hb + (size_t)s0 * HS + c0;
        if constexpr (VEC == 8) {
            u16x8 v0 = *(const u16x8*)hp0;
#pragma unroll
            for (int k = 0; k < 8; k++) acc[k] = fmaf(w0, bf2f(v0[k]), acc[k]);
        } else {
            u16x4 v0 = *(const u16x4*)hp0;
#pragma unroll
            for (int k = 0; k < VEC; k++) acc[k] = fmaf(w0, bf2f(v0[k]), acc[k]);
        }
    }

    float inv = 1.f / den;
    if constexpr (!MEAN) {
        u16x8 ov;
#pragma unroll
        for (int k = 0; k < VEC; k++) {
            float v = acc[k] * inv + bias[c0 + k];
            if (do_elu) v = (v > 0.f) ? v : expm1f(v);
            ov[k] = f2bf(v);
        }
        *(u16x8*)((unsigned short*)outB + (size_t)d * HS + c0) = ov;
    } else {
#pragma unroll
        for (int k = 0; k < VEC; k++) red[c0 + k] = acc[k] * inv;
        __syncthreads();
        if (t < 128) {
#pragma unroll
            for (int k = 0; k < 4; k++) {
                int c = t * 4 + k;
                outF[(size_t)d * 512 + c] = 0.5f * (red[c] + red[c + 512]) + bias[c];
            }
        }
    }
}

// ---------------------------------------------------------------------------
extern "C" void kernel_launch(void* const* d_in, const int* in_sizes, int n_in,
                              void* d_out, int out_size, void* d_ws, size_t ws_size,
                              hipStream_t stream) {
    const float* x      = (const float*)d_in[0];
    const int*   ei     = (const int*)  d_in[1];
    const float* proj_w = (const float*)d_in[2];
    const float* proj_b = (const float*)d_in[3];
    const float* w1  = (const float*)d_in[4];
    const float* as1 = (const float*)d_in[5];
    const float* ad1 = (const float*)d_in[6];
    const float* b1  = (const float*)d_in[7];
    const float* w2  = (const float*)d_in[8];
    const float* as2 = (const float*)d_in[9];
    const float* ad2 = (const float*)d_in[10];
    const float* b2  = (const float*)d_in[11];
    const float* w3  = (const float*)d_in[12];
    const float* as3 = (const float*)d_in[13];
    const float* ad3 = (const float*)d_in[14];
    const float* b3  = (const float*)d_in[15];

    const int n    = in_sizes[0] / 256;   // 10000
    const int E    = in_sizes[1] / 2;     // 160000
    const int Et   = E + n;               // 170000
    const int MB   = CDIV(n, 128);        // 79
    const int Mpad = MB * 128;            // 10112
    const int XT   = CDIV(MB, 8);         // 10 M-tiles per XCD stripe

    char* p = (char*)d_ws;
    auto carve = [&](size_t bytes) {
        void* r = (void*)p;
        p += (bytes + 255) & ~(size_t)255;
        return r;
    };
    __hip_bfloat16* h_bf   = (__hip_bfloat16*)carve((size_t)Mpad * 2048 * sizeof(__hip_bfloat16));
    __hip_bfloat16* act_bf = (__hip_bfloat16*)carve((size_t)Mpad * 2048 * sizeof(__hip_bfloat16));
    __hip_bfloat16* x_bf   = (__hip_bfloat16*)carve((size_t)Mpad * 256 * sizeof(__hip_bfloat16));
    __hip_bfloat16* h0_bf  = (__hip_bfloat16*)carve((size_t)Mpad * 512 * sizeof(__hip_bfloat16));
    __hip_bfloat16* pwt    = (__hip_bfloat16*)carve((size_t)512 * 256 * sizeof(__hip_bfloat16));
    __hip_bfloat16* w1t    = (__hip_bfloat16*)carve((size_t)2048 * 512 * sizeof(__hip_bfloat16));
    __hip_bfloat16* w2t    = (__hip_bfloat16*)carve((size_t)2048 * 2048 * sizeof(__hip_bfloat16));
    __hip_bfloat16* w3t    = (__hip_bfloat16*)carve((size_t)1024 * 2048 * sizeof(__hip_bfloat16));
    float* es  = (float*)carve((size_t)n * 4 * sizeof(float));
    float* ed  = (float*)carve((size_t)n * 4 * sizeof(float));
    int* deg = (int*)carve((size_t)n * sizeof(int));
    int* cur = (int*)carve((size_t)n * sizeof(int));
    int* off = (int*)carve((size_t)(n + 1) * sizeof(int));
    int* csr = (int*)carve((size_t)Et * sizeof(int));
    (void)ws_size; (void)n_in;

    // --- CSR build ---
    hipMemsetAsync(deg, 0, n * sizeof(int), stream);
    hipMemsetAsync(cur, 0, n * sizeof(int), stream);
    hist_kernel<<<CDIV(Et, 256), 256, 0, stream>>>(ei, deg, E, Et);
    scan_kernel<<<1, 1024, 0, stream>>>(deg, off, n);
    scatter_kernel<<<CDIV(Et, 256), 256, 0, stream>>>(ei, off, cur, csr, E, Et);

    // --- weight transpose+convert, x convert ---
    wt_transpose_kernel<<<dim3(256 / 32, 512 / 32),  256, 0, stream>>>(proj_w, pwt, 256, 512);
    wt_transpose_kernel<<<dim3(512 / 32, 2048 / 32), 256, 0, stream>>>(w1, w1t, 512, 2048);
    wt_transpose_kernel<<<dim3(2048 / 32, 2048 / 32),256, 0, stream>>>(w2, w2t, 2048, 2048);
    wt_transpose_kernel<<<dim3(2048 / 32, 1024 / 32),256, 0, stream>>>(w3, w3t, 2048, 1024);
    cvt_bf16_kernel<<<CDIV(n * 256, 256), 256, 0, stream>>>(x, x_bf, n * 256);

    // GEMM grid: 8 XCDs x XT x NB (swizzled inside kernel)
    auto gemm_grid = [&](int NB) { return 8 * XT * NB; };

    // --- proj: h0_bf = bf16(x @ proj_w + proj_b)   [n,512] ---
    gemm_bf16_kernel<<<gemm_grid(4), 256, 0, stream>>>(
        x_bf, pwt, proj_b, h0_bf, n, 512, 256, MB, 4, XT);

    // --- layer 1 (H=4, concat, ELU) ---
    gemm_bf16_kernel<<<gemm_grid(16), 256, 0, stream>>>(
        h0_bf, w1t, nullptr, h_bf, n, 2048, 512, MB, 16, XT);
    esed_kernel<<<n, 4 * 64, 0, stream>>>(h_bf, as1, ad1, es, ed, 4);
    agg_kernel<4, 8, false><<<n, 256, 0, stream>>>(h_bf, es, ed, csr, off, b1,
                                                   nullptr, act_bf, 1);

    // --- layer 2 (H=4, concat, ELU) ---
    gemm_bf16_kernel<<<gemm_grid(16), 256, 0, stream>>>(
        act_bf, w2t, nullptr, h_bf, n, 2048, 2048, MB, 16, XT);
    esed_kernel<<<n, 4 * 64, 0, stream>>>(h_bf, as2, ad2, es, ed, 4);
    agg_kernel<4, 8, false><<<n, 256, 0, stream>>>(h_bf, es, ed, csr, off, b2,
                                                   nullptr, act_bf, 1);

    // --- layer 3 (H=2, mean+bias fused, no ELU) ---
    gemm_bf16_kernel<<<gemm_grid(8), 256, 0, stream>>>(
        act_bf, w3t, nullptr, h_bf, n, 1024, 2048, MB, 8, XT);
    esed_kernel<<<n, 2 * 64, 0, stream>>>(h_bf, as3, ad3, es, ed, 2);
    agg_kernel<2, 4, true><<<n, 256, 0, stream>>>(h_bf, es, ed, csr, off, b3,
                                                  (float*)d_out, nullptr, 0);
}